// Round 12
// baseline (142.450 us; speedup 1.0000x reference)
//
#include <hip/hip_runtime.h>
#include <math.h>

#define NPIX 4096
#define CHSZ 3145728   // one num partial: 24*32*4096 floats
#define NRMSZ 98304    // one nrm partial: 24*4096 floats

// ---------------------------------------------------------------------------
// DPP-based 64-lane inclusive scan (VALU only, no LDS traffic)
// ---------------------------------------------------------------------------
template <int CTRL, int RM>
__device__ __forceinline__ float dpp_add(float x) {
    int xi = __builtin_bit_cast(int, x);
    int sh = __builtin_amdgcn_update_dpp(0, xi, CTRL, RM, 0xf, false);
    return x + __builtin_bit_cast(float, sh);
}

__device__ __forceinline__ float wave_iscan(float x) {
    x = dpp_add<0x111, 0xf>(x);   // row_shr:1
    x = dpp_add<0x112, 0xf>(x);   // row_shr:2
    x = dpp_add<0x114, 0xf>(x);   // row_shr:4
    x = dpp_add<0x118, 0xf>(x);   // row_shr:8
    x = dpp_add<0x142, 0xa>(x);   // row_bcast:15 -> rows 1,3
    x = dpp_add<0x143, 0xc>(x);   // row_bcast:31 -> rows 2,3
    return x;
}

// LDS-only barrier: drain lgkm (ds ops) but leave global loads in flight.
__device__ __forceinline__ void lds_barrier() {
    asm volatile("s_waitcnt lgkmcnt(0)" ::: "memory");
    __builtin_amdgcn_s_barrier();
    __builtin_amdgcn_sched_barrier(0);
}

// ---------------------------------------------------------------------------
// Kernel 1: fused QKV 1x1-conv GEMM, 128px x 32out tiles + register prefetch
// (unchanged from R7/R9).
// ---------------------------------------------------------------------------
__global__ __launch_bounds__(256) void qkv_kernel(
    const float* __restrict__ x, const float* __restrict__ Wq,
    const float* __restrict__ Wk, const float* __restrict__ Wv,
    float* __restrict__ qo, float* __restrict__ ko, float* __restrict__ vo)
{
    const int pt = blockIdx.x * 128;
    const int ot = blockIdx.y * 32;
    const int mat = blockIdx.z;
    const float* __restrict__ W = (mat == 0) ? Wq : ((mat == 1) ? Wk : Wv);
    float* __restrict__ out = (mat == 0) ? qo : ((mat == 1) ? ko : vo);

    __shared__ __align__(16) float Xs[32][132];
    __shared__ __align__(16) float Wt[32][36];   // [c][o]

    const int t = threadIdx.x;
    const int pc = t & 31;
    const int oc = t >> 5;
    const int xc = t >> 5;
    const int xp = (t & 31) << 2;
    const int lo = t >> 3;
    const int lg = (t & 7) << 2;

    float4 xf[4];
    float4 wf;
#pragma unroll
    for (int i = 0; i < 4; i++)
        xf[i] = *reinterpret_cast<const float4*>(x + (xc + 8 * i) * NPIX + pt + xp);
    wf = *reinterpret_cast<const float4*>(W + (ot + lo) * 256 + lg);

    float acc[4][4];
#pragma unroll
    for (int j = 0; j < 4; j++)
#pragma unroll
        for (int i = 0; i < 4; i++) acc[j][i] = 0.f;

    for (int kt = 0; kt < 256; kt += 32) {
#pragma unroll
        for (int i = 0; i < 4; i++)
            *reinterpret_cast<float4*>(&Xs[xc + 8 * i][xp]) = xf[i];
        Wt[lg + 0][lo] = wf.x;
        Wt[lg + 1][lo] = wf.y;
        Wt[lg + 2][lo] = wf.z;
        Wt[lg + 3][lo] = wf.w;
        __syncthreads();
        if (kt + 32 < 256) {
#pragma unroll
            for (int i = 0; i < 4; i++)
                xf[i] = *reinterpret_cast<const float4*>(
                    x + (kt + 32 + xc + 8 * i) * NPIX + pt + xp);
            wf = *reinterpret_cast<const float4*>(W + (ot + lo) * 256 + kt + 32 + lg);
        }
#pragma unroll
        for (int kk = 0; kk < 32; kk++) {
            float4 a = *reinterpret_cast<const float4*>(&Xs[kk][pc << 2]);
            float av[4] = {a.x, a.y, a.z, a.w};
            float4 b4 = *reinterpret_cast<const float4*>(&Wt[kk][oc << 2]);
            float bv[4] = {b4.x, b4.y, b4.z, b4.w};
#pragma unroll
            for (int j = 0; j < 4; j++)
#pragma unroll
                for (int i = 0; i < 4; i++)
                    acc[j][i] = fmaf(bv[j], av[i], acc[j][i]);
        }
        __syncthreads();
    }

    if (mat < 2) {
#pragma unroll
        for (int j = 0; j < 4; j++) {
            const int o = ot + (oc << 2) + j;
            float4 r;
            r.x = 1.f / (1.f + __expf(-acc[j][0]));
            r.y = 1.f / (1.f + __expf(-acc[j][1]));
            r.z = 1.f / (1.f + __expf(-acc[j][2]));
            r.w = 1.f / (1.f + __expf(-acc[j][3]));
            *reinterpret_cast<float4*>(out + o * NPIX + pt + (pc << 2)) = r;
        }
    } else {
        float* scratch = &Xs[0][0];
        __syncthreads();
#pragma unroll
        for (int i = 0; i < 4; i++) {
            float ss = 0.f;
#pragma unroll
            for (int j = 0; j < 4; j++) ss += acc[j][i] * acc[j][i];
            scratch[oc * 128 + (pc << 2) + i] = ss;
        }
        __syncthreads();
        float scale[4];
#pragma unroll
        for (int i = 0; i < 4; i++) {
            float tot = 0.f;
#pragma unroll
            for (int g = 0; g < 8; g++) tot += scratch[g * 128 + (pc << 2) + i];
            scale[i] = 1.f / fmaxf(sqrtf(tot), 1e-12f);
        }
#pragma unroll
        for (int j = 0; j < 4; j++) {
            const int o = ot + (oc << 2) + j;
            float4 r;
            r.x = acc[j][0] * scale[0];
            r.y = acc[j][1] * scale[1];
            r.z = acc[j][2] * scale[2];
            r.w = acc[j][3] * scale[3];
            *reinterpret_cast<float4*>(out + o * NPIX + pt + (pc << 2)) = r;
        }
    }
}

// ---------------------------------------------------------------------------
// Kernel 2: fused integral-image + windowed contraction, 512 threads (8 waves).
// R12: ONE barrier per d-iter via double-buffered Pt:
//   body(d): {off+store P(d)->Pt[d&1] | qload(d) | iscan(d+1) | kload(d+2)}
//            -> barrier -> phase4(d) reads Pt[d&1]
// Hazards: store(d+2) into Pt[d&1] is separated from phase4(d) by barrier(d+1);
// csum double-buffered the same way. Pt shrunk to [65][68] (17.7 KB):
//  - y<=0 zero pad is provably never read (quads 4-aligned; full-zero quads
//    skipped; partial straddle impossible since y0,hw == 0 mod 4)
//  - bottom replicate pad replaced by wave-uniform splat of P[64] when
//    y0+hw >= 64 (straddle impossible, same mod-4 argument)
// LDS 2*17.7 + 2*2.2 = 39.7 KB. All register-array loops compile-time (R8).
// VGPR target <= 85 (6 waves/SIMD, 3 blocks/CU); R4: cliffs halve residency.
// ---------------------------------------------------------------------------
template <int PD>
__global__ __launch_bounds__(512) void attn_kernel(
    const float* __restrict__ q, const float* __restrict__ k,
    const float* __restrict__ v, float* __restrict__ num, float* __restrict__ nrm)
{
    const int f = blockIdx.x;          // 0..32 (32 == norm slot)
    const int head = blockIdx.y;       // 0..7
    const int dg = blockIdx.z;         // 0..(32/PD - 1)
    const bool isnorm = (f == 32);

    const float* __restrict__ kh = k + (head * 32 + dg * PD) * NPIX;
    const float* __restrict__ qh = q + (head * 32 + dg * PD) * NPIX;
    const float* __restrict__ vf = v + (head * 32 + (isnorm ? 0 : f)) * NPIX;

    __shared__ __align__(16) float Pt[2][65][68];   // 2 x 17,680 B
    __shared__ float csum[2][8][68];                // 2 x 2,176 B

    const int t = threadIdx.x;
    const int lane = t & 63;
    const int wv = t >> 6;             // 0..7

    // zero-init both buffers once; x=0 column and row yp=0 stay zero forever
    for (int i = t; i < 2 * 65 * 68; i += 512) (&Pt[0][0][0])[i] = 0.f;

    float vreg[8], kcur[8];
#pragma unroll
    for (int i = 0; i < 8; i++) {
        const int r = wv * 8 + i;
        vreg[i] = isnorm ? 1.f : vf[r * 64 + lane];
        kcur[i] = kh[r * 64 + lane];
    }

    float acc[3][8];
#pragma unroll
    for (int w = 0; w < 3; w++)
#pragma unroll
        for (int i = 0; i < 8; i++) acc[w][i] = 0.f;

    // prologue: iscan(0) -> pv, csum[0]; prefetch k(1)
    float pv[8], runcur;
    {
        float run = 0.f;
#pragma unroll
        for (int i = 0; i < 8; i++) {
            float rs = wave_iscan(kcur[i] * vreg[i]);
            pv[i] = run;               // exclusive prefix: P row (8*wv + i)
            run += rs;
        }
        csum[0][wv][lane] = run;
        runcur = run;
        if (PD > 1) {
#pragma unroll
            for (int i = 0; i < 8; i++)
                kcur[i] = kh[1 * NPIX + (wv * 8 + i) * 64 + lane];
        }
    }
    lds_barrier();                     // zero-init + csum(0) visible

    float pvn[8], runn;
    for (int dd = 0; dd < PD; dd++) {
        const int b = dd & 1;
        // off(dd) + store P(dd) into Pt[b]
        float off = 0.f;
#pragma unroll
        for (int w2 = 0; w2 < 7; w2++) if (w2 < wv) off += csum[b][w2][lane];
#pragma unroll
        for (int s = 0; s < 2; s++) {
            float4 r4 = make_float4(pv[4 * s] + off, pv[4 * s + 1] + off,
                                    pv[4 * s + 2] + off, pv[4 * s + 3] + off);
            *reinterpret_cast<float4*>(&Pt[b][lane + 1][wv * 8 + 4 * s]) = r4;
        }
        if (wv == 7) Pt[b][lane + 1][64] = off + runcur;   // row y=64 total
        // qload(dd) -- consumed in phase4 after the barrier (vmcnt in flight)
        float qv[8];
#pragma unroll
        for (int g = 0; g < 2; g++)
#pragma unroll
            for (int j = 0; j < 4; j++)
                qv[g * 4 + j] = qh[dd * NPIX + ((wv + 8 * g) * 4 + j) * 64 + lane];
        // iscan(dd+1) into pvn + csum[b^1]; then reuse kcur for k(dd+2)
        if (dd + 1 < PD) {
            float run = 0.f;
#pragma unroll
            for (int i = 0; i < 8; i++) {
                float rs = wave_iscan(kcur[i] * vreg[i]);
                pvn[i] = run;
                run += rs;
            }
            csum[b ^ 1][wv][lane] = run;
            runn = run;
            if (dd + 2 < PD) {
#pragma unroll
                for (int i = 0; i < 8; i++)
                    kcur[i] = kh[(dd + 2) * NPIX + (wv * 8 + i) * 64 + lane];
            }
        }
        lds_barrier();                 // the ONLY barrier per d-iter
        // phase4(dd) reads Pt[b]
#pragma unroll
        for (int g = 0; g < 2; g++) {
            const int y0 = (wv + 8 * g) * 4;
#pragma unroll
            for (int w = 0; w < 3; w++) {
                const int hw = 32 >> w;
                const int xlo = max(lane - hw, 0);
                const int xhi = min(lane + hw, 64);
                float c0, c1, c2, c3;
                if (y0 + 3 <= hw) {
                    // low corners fully in zero region: contr = A - B
                    float4 A4 = *reinterpret_cast<const float4*>(&Pt[b][xhi][y0 + hw]);
                    float4 B4 = *reinterpret_cast<const float4*>(&Pt[b][xlo][y0 + hw]);
                    c0 = A4.x - B4.x; c1 = A4.y - B4.y;
                    c2 = A4.z - B4.z; c3 = A4.w - B4.w;
                } else if (y0 + hw >= 64) {
                    // high corners clamp to row 64 (wave-uniform splat)
                    float As = Pt[b][xhi][64];
                    float Bs = Pt[b][xlo][64];
                    float4 C4 = *reinterpret_cast<const float4*>(&Pt[b][xhi][y0 - hw]);
                    float4 E4 = *reinterpret_cast<const float4*>(&Pt[b][xlo][y0 - hw]);
                    const float ab = As - Bs;
                    c0 = ab - (C4.x - E4.x); c1 = ab - (C4.y - E4.y);
                    c2 = ab - (C4.z - E4.z); c3 = ab - (C4.w - E4.w);
                } else {
                    float4 A4 = *reinterpret_cast<const float4*>(&Pt[b][xhi][y0 + hw]);
                    float4 B4 = *reinterpret_cast<const float4*>(&Pt[b][xlo][y0 + hw]);
                    float4 C4 = *reinterpret_cast<const float4*>(&Pt[b][xhi][y0 - hw]);
                    float4 E4 = *reinterpret_cast<const float4*>(&Pt[b][xlo][y0 - hw]);
                    c0 = (A4.x - B4.x) - (C4.x - E4.x);
                    c1 = (A4.y - B4.y) - (C4.y - E4.y);
                    c2 = (A4.z - B4.z) - (C4.z - E4.z);
                    c3 = (A4.w - B4.w) - (C4.w - E4.w);
                }
                acc[w][g * 4 + 0] = fmaf(qv[g * 4 + 0], c0, acc[w][g * 4 + 0]);
                acc[w][g * 4 + 1] = fmaf(qv[g * 4 + 1], c1, acc[w][g * 4 + 1]);
                acc[w][g * 4 + 2] = fmaf(qv[g * 4 + 2], c2, acc[w][g * 4 + 2]);
                acc[w][g * 4 + 3] = fmaf(qv[g * 4 + 3], c3, acc[w][g * 4 + 3]);
            }
        }
        // rotate pipeline registers (static indices)
        if (dd + 1 < PD) {
#pragma unroll
            for (int i = 0; i < 8; i++) pv[i] = pvn[i];
            runcur = runn;
        }
    }

    float* __restrict__ nout = num + (size_t)dg * CHSZ;
    float* __restrict__ rout = nrm + (size_t)dg * NRMSZ;
#pragma unroll
    for (int w = 0; w < 3; w++) {
#pragma unroll
        for (int g = 0; g < 2; g++) {
#pragma unroll
            for (int j = 0; j < 4; j++) {
                const int px = ((wv + 8 * g) * 4 + j) * 64 + lane;
                const float val = acc[w][g * 4 + j];
                if (isnorm) rout[(w * 8 + head) * NPIX + px] = val;
                else        nout[((w * 8 + head) * 32 + f) * NPIX + px] = val;
            }
        }
    }
}

// ---------------------------------------------------------------------------
// Kernel 3: final 1x1 conv partial; acc[4][4], 64px x 64out tiles, K-split
// across z (12 of 24 channels each). grid (64, 4, 2). (unchanged from R11)
// ---------------------------------------------------------------------------
template <int NS>
__global__ __launch_bounds__(256) void out_kernel(
    const float* __restrict__ num, const float* __restrict__ nrm,
    const float* __restrict__ Wout, float* __restrict__ obuf)
{
    const int pt = blockIdx.x * 64;
    const int ot = blockIdx.y * 64;
    const int kt0 = blockIdx.z * 12;
    __shared__ __align__(16) float As[32][68];
    __shared__ __align__(16) float Wt[32][68];   // [c][o]
    const int t = threadIdx.x;
    const int pc = t & 15;
    const int oc = t >> 4;
    const int xc = t >> 4;
    const int xp = (t & 15) << 2;
    const int lo = t & 63;
    const int lc = (t >> 6) << 2;

    float4 nv[NS][2], mv[NS], wf[2];
#pragma unroll
    for (int s = 0; s < NS; s++) {
#pragma unroll
        for (int i = 0; i < 2; i++)
            nv[s][i] = *reinterpret_cast<const float4*>(
                num + (size_t)s * CHSZ + (size_t)(kt0 * 32 + xc + 16 * i) * NPIX + pt + xp);
        mv[s] = *reinterpret_cast<const float4*>(
            nrm + (size_t)s * NRMSZ + kt0 * NPIX + pt + xp);
    }
    wf[0] = *reinterpret_cast<const float4*>(Wout + (ot + lo) * 768 + kt0 * 32 + lc);
    wf[1] = *reinterpret_cast<const float4*>(Wout + (ot + lo) * 768 + kt0 * 32 + lc + 16);

    float acc[4][4];
#pragma unroll
    for (int j = 0; j < 4; j++)
#pragma unroll
        for (int i = 0; i < 4; i++) acc[j][i] = 0.f;

    for (int kt = kt0; kt < kt0 + 12; kt++) {
        float4 ms = mv[0];
#pragma unroll
        for (int s = 1; s < NS; s++) {
            ms.x += mv[s].x; ms.y += mv[s].y; ms.z += mv[s].z; ms.w += mv[s].w;
        }
        float4 rv;
        rv.x = 1.f / (ms.x + 1e-6f); rv.y = 1.f / (ms.y + 1e-6f);
        rv.z = 1.f / (ms.z + 1e-6f); rv.w = 1.f / (ms.w + 1e-6f);
#pragma unroll
        for (int i = 0; i < 2; i++) {
            float4 r = nv[0][i];
#pragma unroll
            for (int s = 1; s < NS; s++) {
                r.x += nv[s][i].x; r.y += nv[s][i].y;
                r.z += nv[s][i].z; r.w += nv[s][i].w;
            }
            r.x *= rv.x; r.y *= rv.y; r.z *= rv.z; r.w *= rv.w;
            *reinterpret_cast<float4*>(&As[xc + 16 * i][xp]) = r;
        }
#pragma unroll
        for (int i = 0; i < 2; i++) {
            Wt[lc + 16 * i + 0][lo] = wf[i].x;
            Wt[lc + 16 * i + 1][lo] = wf[i].y;
            Wt[lc + 16 * i + 2][lo] = wf[i].z;
            Wt[lc + 16 * i + 3][lo] = wf[i].w;
        }
        __syncthreads();
        if (kt + 1 < kt0 + 12) {
#pragma unroll
            for (int s = 0; s < NS; s++) {
#pragma unroll
                for (int i = 0; i < 2; i++)
                    nv[s][i] = *reinterpret_cast<const float4*>(
                        num + (size_t)s * CHSZ +
                        (size_t)((kt + 1) * 32 + xc + 16 * i) * NPIX + pt + xp);
                mv[s] = *reinterpret_cast<const float4*>(
                    nrm + (size_t)s * NRMSZ + (kt + 1) * NPIX + pt + xp);
            }
            wf[0] = *reinterpret_cast<const float4*>(
                Wout + (ot + lo) * 768 + (kt + 1) * 32 + lc);
            wf[1] = *reinterpret_cast<const float4*>(
                Wout + (ot + lo) * 768 + (kt + 1) * 32 + lc + 16);
        }
#pragma unroll
        for (int kk = 0; kk < 32; kk++) {
            float4 a = *reinterpret_cast<const float4*>(&As[kk][pc << 2]);
            float av[4] = {a.x, a.y, a.z, a.w};
            float4 b4 = *reinterpret_cast<const float4*>(&Wt[kk][oc << 2]);
            float bv[4] = {b4.x, b4.y, b4.z, b4.w};
#pragma unroll
            for (int j = 0; j < 4; j++)
#pragma unroll
                for (int i = 0; i < 4; i++)
                    acc[j][i] = fmaf(bv[j], av[i], acc[j][i]);
        }
        __syncthreads();
    }

    float* __restrict__ ob = obuf + (size_t)blockIdx.z * 1048576;
#pragma unroll
    for (int j = 0; j < 4; j++) {
        const int o = ot + (oc << 2) + j;
        float4 r;
        r.x = acc[j][0]; r.y = acc[j][1]; r.z = acc[j][2]; r.w = acc[j][3];
        *reinterpret_cast<float4*>(ob + o * NPIX + pt + (pc << 2)) = r;
    }
}

// ---------------------------------------------------------------------------
// Kernel 4: merge K-split partials + bias. (unchanged from R11)
// ---------------------------------------------------------------------------
__global__ __launch_bounds__(256) void kmerge_kernel(
    const float* __restrict__ obuf, const float* __restrict__ bout,
    float* __restrict__ out)
{
    const int i4 = (blockIdx.x * 256 + threadIdx.x) * 4;
    const float bb = bout[i4 >> 12];
    float4 a = *reinterpret_cast<const float4*>(obuf + i4);
    float4 b = *reinterpret_cast<const float4*>(obuf + 1048576 + i4);
    float4 r;
    r.x = a.x + b.x + bb;
    r.y = a.y + b.y + bb;
    r.z = a.z + b.z + bb;
    r.w = a.w + b.w + bb;
    *reinterpret_cast<float4*>(out + i4) = r;
}

extern "C" void kernel_launch(void* const* d_in, const int* in_sizes, int n_in,
                              void* d_out, int out_size, void* d_ws, size_t ws_size,
                              hipStream_t stream)
{
    const float* x    = (const float*)d_in[0];
    const float* Wq   = (const float*)d_in[1];
    const float* Wk   = (const float*)d_in[2];
    const float* Wv   = (const float*)d_in[3];
    const float* Wout = (const float*)d_in[4];
    const float* bout = (const float*)d_in[5];
    float* out = (float*)d_out;

    float* ws = (float*)d_ws;
    float* q   = ws;                  // 1,048,576 floats
    float* k   = ws + 1048576;
    float* v   = ws + 2097152;
    float* num = ws + 3145728;        // NS partials of CHSZ, then NS of NRMSZ
    float* obuf = ws;                 // 2 x 1,048,576 — aliases dead q/k
    const size_t fl = ws_size / 4;

    qkv_kernel<<<dim3(32, 8, 3), 256, 0, stream>>>(x, Wq, Wk, Wv, q, k, v);

    if (fl >= 3145728 + (size_t)4 * (CHSZ + NRMSZ)) {        // NS = 4
        float* nrm = num + (size_t)4 * CHSZ;
        attn_kernel<8><<<dim3(33, 8, 4), 512, 0, stream>>>(q, k, v, num, nrm);
        out_kernel<4><<<dim3(64, 4, 2), 256, 0, stream>>>(num, nrm, Wout, obuf);
    } else if (fl >= 3145728 + (size_t)2 * (CHSZ + NRMSZ)) { // NS = 2
        float* nrm = num + (size_t)2 * CHSZ;
        attn_kernel<16><<<dim3(33, 8, 2), 512, 0, stream>>>(q, k, v, num, nrm);
        out_kernel<2><<<dim3(64, 4, 2), 256, 0, stream>>>(num, nrm, Wout, obuf);
    } else {                                                 // NS = 1
        float* nrm = num + CHSZ;
        attn_kernel<32><<<dim3(33, 8, 1), 512, 0, stream>>>(q, k, v, num, nrm);
        out_kernel<1><<<dim3(64, 4, 2), 256, 0, stream>>>(num, nrm, Wout, obuf);
    }
    kmerge_kernel<<<dim3(1024), 256, 0, stream>>>(obuf, bout, out);
}